// Round 10
// baseline (368.421 us; speedup 1.0000x reference)
//
#include <hip/hip_runtime.h>
#include <hip/hip_bf16.h>

typedef __hip_bfloat16 bf16;
typedef __attribute__((ext_vector_type(8))) short bf16x8v;  // 8 bf16 = 4 VGPRs
typedef __attribute__((ext_vector_type(4))) float f32x4v;   // MFMA accumulator

// ---------- helpers -----------------------------------------------------------
__device__ __forceinline__ float bfbits2f(unsigned short h) {
    union { unsigned int u; float f; } v; v.u = ((unsigned int)h) << 16; return v.f;
}
__device__ __forceinline__ unsigned short f2bfbits(float f) {
    bf16 h = __float2bfloat16(f);
    unsigned short s;
    __builtin_memcpy(&s, &h, 2);
    return s;
}
__device__ __forceinline__ float load1_any(const void* p, long idx, bool f32) {
    if (f32) return ((const float*)p)[idx];
    return bfbits2f(((const unsigned short*)p)[idx]);
}
__device__ __forceinline__ float4 loadbf4(const bf16* p) {
    ushort4 u = *reinterpret_cast<const ushort4*>(p);
    return make_float4(bfbits2f(u.x), bfbits2f(u.y), bfbits2f(u.z), bfbits2f(u.w));
}
__device__ __forceinline__ void store_bf4(bf16* p, float a, float b, float c, float d) {
    ushort4 o;
    o.x = f2bfbits(a); o.y = f2bfbits(b); o.z = f2bfbits(c); o.w = f2bfbits(d);
    *reinterpret_cast<ushort4*>(p) = o;
}
// async global->LDS, 16B per lane; LDS dest = wave-uniform base + lane*16
__device__ __forceinline__ void gl16(const void* g, void* l) {
    __builtin_amdgcn_global_load_lds(
        (const __attribute__((address_space(1))) unsigned int*)g,
        (__attribute__((address_space(3))) unsigned int*)l, 16, 0, 0);
}

// ---------- input dtype detection (flag[0]=1: raw inputs are fp32) ------------
// Also writes flag[1]=1 (constant "fp32" flag for internally-built fp32 arrays).
__global__ __launch_bounds__(1024)
void detect_kernel(const unsigned short* __restrict__ x, int* __restrict__ flag) {
    const int tid = threadIdx.x;
    int zc = 0, hc = 0;
    const uint4* xv = (const uint4*)x;
#pragma unroll
    for (int p = 0; p < 16; ++p) {
        uint4 v = xv[p * 1024 + tid];
        unsigned s0 = v.x & 0xFFFFu, s1 = v.y & 0xFFFFu;
        unsigned s2 = v.z & 0xFFFFu, s3 = v.w & 0xFFFFu;
        zc += (int)(s0 == 0) + (int)(s1 == 0) + (int)(s2 == 0) + (int)(s3 == 0);
        hc += (int)(((s0 >> 7) & 0xFFu) >= 0x90u) + (int)(((s1 >> 7) & 0xFFu) >= 0x90u)
            + (int)(((s2 >> 7) & 0xFFu) >= 0x90u) + (int)(((s3 >> 7) & 0xFFu) >= 0x90u);
    }
#pragma unroll
    for (int off = 32; off > 0; off >>= 1) {
        zc += __shfl_down(zc, off);
        hc += __shfl_down(hc, off);
    }
    __shared__ int rz[16], rh[16];
    if ((tid & 63) == 0) { rz[tid >> 6] = zc; rh[tid >> 6] = hc; }
    __syncthreads();
    if (tid == 0) {
        int Z = 0, H = 0;
#pragma unroll
        for (int i = 0; i < 16; ++i) { Z += rz[i]; H += rh[i]; }
        flag[0] = (Z > 60000 || H > 256) ? 1 : 0;
        flag[1] = 1;
    }
}

__global__ void diag_kernel(float* __restrict__ out, float val) {
    if (threadIdx.x == 0) out[0] = val;
}

// ---------- fused setup convert: 6 weights + Wleft + bcat in one dispatch -----
// ranges: [0,4456448) = 6 weight tensors -> bf16
//         [4456448,4849664) = Wleft (768x512) = [w_cdc ; w_sv|0 ; 0|w_fv] bf16
//         [4849664,4850432) = bcat fp32 [b_cdc;b_sv;b_fv]
__global__ __launch_bounds__(256)
void convert6_kernel(const void* __restrict__ s0, const void* __restrict__ s1,
                     const void* __restrict__ s2, const void* __restrict__ s3,
                     const void* __restrict__ s4, const void* __restrict__ s5,
                     const void* __restrict__ b0, const void* __restrict__ b1,
                     const void* __restrict__ b2,
                     bf16* __restrict__ dst, bf16* __restrict__ wl,
                     float* __restrict__ bc, const int* __restrict__ dflag) {
    const bool f32 = (*dflag != 0);
    for (long i = (long)blockIdx.x * 256 + threadIdx.x; i < 4850432;
         i += (long)gridDim.x * 256) {
        if (i < 4456448) {
            const void* s; long o;
            if (i < 131072)       { s = s0; o = i; }
            else if (i < 196608)  { s = s1; o = i - 131072; }
            else if (i < 262144)  { s = s2; o = i - 196608; }
            else if (i < 2359296) { s = s3; o = i - 262144; }
            else if (i < 3407872) { s = s4; o = i - 2359296; }
            else                  { s = s5; o = i - 3407872; }
            dst[i] = __float2bfloat16(load1_any(s, o, f32));
        } else if (i < 4849664) {
            long j = i - 4456448;
            int r = (int)(j >> 9), c = (int)(j & 511);
            float v = 0.f;
            if (r < 256) v = load1_any(s0, r * 512 + c, f32);
            else if (r < 512) { if (c < 256) v = load1_any(s1, (r - 256) * 256 + c, f32); }
            else              { if (c >= 256) v = load1_any(s2, (r - 512) * 256 + (c - 256), f32); }
            wl[j] = __float2bfloat16(v);
        } else {
            long j = i - 4849664;
            float v = (j < 256) ? load1_any(b0, j, f32)
                    : (j < 512) ? load1_any(b1, j - 256, f32)
                                : load1_any(b2, j - 512, f32);
            bc[j] = v;
        }
    }
}

// ---------- bf16 transpose 1024x1024 (for w_qk_hi) ----------------------------
__global__ __launch_bounds__(256)
void xpose_w_kernel(const bf16* __restrict__ src, bf16* __restrict__ dst) {
    __shared__ float t[64][65];
    const int c0 = blockIdx.x * 64, r0 = blockIdx.y * 64;
    const int tid = threadIdx.x;
#pragma unroll
    for (int p = 0; p < 16; ++p) {
        int e = tid + p * 256; int r = e >> 6, c = e & 63;
        t[r][c] = __bfloat162float(src[(long)(r0 + r) * 1024 + c0 + c]);
    }
    __syncthreads();
#pragma unroll
    for (int p = 0; p < 16; ++p) {
        int e = tid + p * 256; int r = e >> 6, c = e & 63;
        dst[(long)(c0 + r) * 1024 + r0 + c] = __float2bfloat16(t[c][r]);
    }
}

// ---------- transpose+convert: x[bg][256][1024] raw -> xT[z][1024][256] bf16 --
__global__ __launch_bounds__(256)
void xpose_conv_kernel(const void* __restrict__ x1, const void* __restrict__ x2,
                       bf16* __restrict__ dst, int bofs, int zsplit,
                       const int* __restrict__ dflag) {
    const bool f32 = (*dflag != 0);
    __shared__ float t[64][65];
    const int ch0 = blockIdx.y * 64, n0 = blockIdx.x * 64, z = blockIdx.z;
    const bool hiz = (z >= zsplit);
    const int zl = hiz ? z - zsplit : z;
    const void* x = hiz ? x2 : x1;
    const long sb = (long)(zl + bofs) * 262144, db = (long)z * 262144;
    const int tid = threadIdx.x;
#pragma unroll
    for (int p = 0; p < 16; ++p) {
        int e = tid + p * 256; int sch = e >> 6, sn = e & 63;
        t[sch][sn] = load1_any(x, sb + (long)(ch0 + sch) * 1024 + n0 + sn, f32);
    }
    __syncthreads();
#pragma unroll
    for (int p = 0; p < 16; ++p) {
        int e = tid + p * 256; int dn = e >> 6, dch = e & 63;
        dst[db + (long)(n0 + dn) * 256 + ch0 + dch] = __float2bfloat16(t[dch][dn]);
    }
}

// ---------- column softmax + fused v-scale ------------------------------------
// X[z'][1024][1024] bf16; softmax over rows j per column n:
//   X <- exp(X - colmax);  then vb[side][c][zn] *= 1/colsum for this block's cols.
__global__ __launch_bounds__(256)
void smnorm_kernel(bf16* __restrict__ X, bf16* __restrict__ vb, int gN, int gq) {
    const int tid = threadIdx.x;
    const int cg = tid & 7;            // col group (8 cols, 16B)
    const int js = tid >> 3;           // row slice (0..31)
    const int n0 = blockIdx.x * 64;
    const long zb = (long)blockIdx.y * 1048576;
    unsigned short* Xp = (unsigned short*)X + zb + n0 + cg * 8;

    float m[8];
#pragma unroll
    for (int q = 0; q < 8; ++q) m[q] = -3.4e38f;
#pragma unroll 4
    for (int r = 0; r < 32; ++r) {
        bf16x8v u = *(const bf16x8v*)(Xp + (long)(js * 32 + r) * 1024);
#pragma unroll
        for (int q = 0; q < 8; ++q)
            m[q] = fmaxf(m[q], bfbits2f((unsigned short)u[q]));
    }
    __shared__ float sh[32][8][8];
    __shared__ float Mc[64];
    __shared__ float Sc[64];
#pragma unroll
    for (int q = 0; q < 8; ++q) sh[js][cg][q] = m[q];
    __syncthreads();
    if (tid < 64) {
        float mm = -3.4e38f;
#pragma unroll 8
        for (int s = 0; s < 32; ++s) mm = fmaxf(mm, sh[s][tid >> 3][tid & 7]);
        Mc[tid] = mm;
    }
    __syncthreads();
    float M8[8], s8[8];
#pragma unroll
    for (int q = 0; q < 8; ++q) { M8[q] = Mc[cg * 8 + q]; s8[q] = 0.f; }
#pragma unroll 4
    for (int r = 0; r < 32; ++r) {
        long off = (long)(js * 32 + r) * 1024;
        bf16x8v u = *(const bf16x8v*)(Xp + off);
        bf16x8v o;
#pragma unroll
        for (int q = 0; q < 8; ++q) {
            float e = __expf(bfbits2f((unsigned short)u[q]) - M8[q]);
            s8[q] += e;
            o[q] = (short)f2bfbits(e);
        }
        *(bf16x8v*)(Xp + off) = o;
    }
    __syncthreads();
#pragma unroll
    for (int q = 0; q < 8; ++q) sh[js][cg][q] = s8[q];
    __syncthreads();
    if (tid < 64) {
        float ss = 0.f;
#pragma unroll 8
        for (int s = 0; s < 32; ++s) ss += sh[s][tid >> 3][tid & 7];
        Sc[tid] = 1.0f / ss;
    }
    __syncthreads();
    // fused: scale vb columns of this (side, z, n0..n0+63) block
    const int side = (blockIdx.y >= (unsigned)gq) ? 1 : 0;
    const int zl = blockIdx.y - side * gq;
    bf16* vp = vb + (long)(side * 256) * gN + (long)zl * 1024 + n0 + cg * 8;
    float is8[8];
#pragma unroll
    for (int q = 0; q < 8; ++q) is8[q] = Sc[cg * 8 + q];
#pragma unroll
    for (int rr = 0; rr < 8; ++rr) {
        long off = (long)(rr * 32 + js) * gN;
        bf16x8v u = *(bf16x8v*)(vp + off);
        bf16x8v o;
#pragma unroll
        for (int q = 0; q < 8; ++q)
            o[q] = (short)f2bfbits(bfbits2f((unsigned short)u[q]) * is8[q]);
        *(bf16x8v*)(vp + off) = o;
    }
}

// ---------- 256-thread BMx128 NT MFMA GEMM, NBUF-ring, counted vmcnt ----------
// D[z][m][n] = sum_k A[z][m][k] * B[z][n][k]   (both k-contiguous).
// BM = MI*32. MI=4: NBUF=3 -> 48KB LDS (3 blk/CU) | NBUF=5 -> 80KB (2 blk/CU,
// distance-4 prefetch ~2300cy of latency cover).
// Ring: prologue stages tiles 0..NBUF-2; loop: wait vmcnt(min(rem,NBUF-2)*L) ->
// barrier -> sched_barrier -> stage(t+NBUF-1) -> ds_read -> MFMA (compiler
// schedules fine-grained lgkmcnt).  L = loads/stage = MI/2+2.
// Buffer-reuse safety: stage(t+NBUF-1) writes buf[(t-1)%NBUF]; its step-(t-1)
// readers consumed all ds_reads via MFMAs before reaching barrier t (in-order
// issue => HW lgkm waits retired), and stage is issued after barrier t.
// XCD swizzle (T1): remap flat id so each XCD owns a contiguous chunk, z slowest.
// EPI: 0 plain bf16 | 1 +bias[row] | 2 *scale+bias[row] | 3 +res, fp32 out
template <int MI, int EPI, int NBUF>
__global__ __launch_bounds__(256)
void mfma_nt(const bf16* __restrict__ A1, const bf16* __restrict__ A2,
             long aB1, long aB2, int ldA1, int ldA2,
             const bf16* __restrict__ B1, const bf16* __restrict__ B2,
             long bB1, long bB2, int ldB1, int ldB2,
             int ksplit, long kOff2,
             void* __restrict__ out1, void* __restrict__ out2,
             long oB1, long oB2, int ldO1, int ldO2,
             int K, float scale,
             const void* __restrict__ bias1, const void* __restrict__ bias2,
             const void* __restrict__ res1, const void* __restrict__ res2,
             long rBatch, int bofs, int zsplit,
             const int* __restrict__ dflag) {
    constexpr int BM = MI * 32;
    constexpr int LPS = MI / 2 + 2;     // gl16 loads per stage per wave
    __shared__ short As[NBUF][BM * 32];
    __shared__ short Bs[NBUF][4096];
    const int tid  = threadIdx.x;
    const int lane = tid & 63, wave = tid >> 6;
    const int quad = lane >> 4, lrow = lane & 15;
    const int wm = (wave >> 1) * (MI * 16), wn = (wave & 1) * 64;

    // ---- XCD-aware block swizzle (bijective when ntot % 8 == 0) ----
    int bx = blockIdx.x, by = blockIdx.y, bz = blockIdx.z;
    {
        const int gx = gridDim.x, gy = gridDim.y;
        const int gxy = gx * gy;
        const int ntot = gxy * gridDim.z;
        if ((ntot & 7) == 0) {
            int flat = bx + gx * (by + gy * bz);
            int w = (flat & 7) * (ntot >> 3) + (flat >> 3);
            bz = w / gxy;
            int rem = w - bz * gxy;
            by = rem / gx;
            bx = rem - by * gx;
        }
    }
    const int z  = bz;
    const bool hiz = (z >= zsplit);
    const int zl = hiz ? z - zsplit : z;
    const int n0 = bx * 128, m0 = by * BM;
    const int ldA = hiz ? ldA2 : ldA1, ldB = hiz ? ldB2 : ldB1;
    const int ldO = hiz ? ldO2 : ldO1;
    const int srow = tid >> 2, sseg = tid & 3;
    const int sl = sseg ^ ((srow >> 1) & 3);        // staging: swizzled seg
    const int xq = quad ^ ((lrow >> 1) & 3);        // read: physical seg

    const bf16* Ab = (hiz ? A2 : A1) + (long)zl * (hiz ? aB2 : aB1);
    const bf16* Bb = (hiz ? B2 : B1) + (long)zl * (hiz ? bB2 : bB1);

    auto stage = [&](int buf, int k0) {
        const bf16* asrc = Ab + (long)k0;
        const bf16* bsrc = Bb + ((k0 < ksplit) ? (long)k0 : (long)(k0 - ksplit) + kOff2);
#pragma unroll
        for (int p = 0; p < MI / 2; ++p)
            gl16(asrc + (long)(m0 + p * 64 + srow) * ldA + sl * 8,
                 &As[buf][p * 2048 + wave * 512]);
        gl16(bsrc + (long)(n0 + srow) * ldB + sl * 8, &Bs[buf][wave * 512]);
        gl16(bsrc + (long)(n0 + 64 + srow) * ldB + sl * 8, &Bs[buf][2048 + wave * 512]);
    };

    f32x4v acc[MI][4] = {};
    const int nt = K >> 5;
    stage(0, 0);
    if (nt > 1) stage(1, 32);
    if constexpr (NBUF >= 5) {
        if (nt > 2) stage(2, 64);
        if (nt > 3) stage(3, 96);
    }

    int cur = 0;
    for (int t = 0; t < nt; ++t) {
        const int rem = nt - 1 - t;
        if constexpr (NBUF == 3) {
            if (rem >= 1) {
                if constexpr (LPS == 4) asm volatile("s_waitcnt vmcnt(4)" ::: "memory");
                else                    asm volatile("s_waitcnt vmcnt(3)" ::: "memory");
            } else {
                asm volatile("s_waitcnt vmcnt(0)" ::: "memory");
            }
        } else {  // NBUF == 5
            if constexpr (LPS == 4) {
                if (rem >= 3)      asm volatile("s_waitcnt vmcnt(12)" ::: "memory");
                else if (rem == 2) asm volatile("s_waitcnt vmcnt(8)" ::: "memory");
                else if (rem == 1) asm volatile("s_waitcnt vmcnt(4)" ::: "memory");
                else               asm volatile("s_waitcnt vmcnt(0)" ::: "memory");
            } else {
                if (rem >= 3)      asm volatile("s_waitcnt vmcnt(9)" ::: "memory");
                else if (rem == 2) asm volatile("s_waitcnt vmcnt(6)" ::: "memory");
                else if (rem == 1) asm volatile("s_waitcnt vmcnt(3)" ::: "memory");
                else               asm volatile("s_waitcnt vmcnt(0)" ::: "memory");
            }
        }
        __builtin_amdgcn_s_barrier();            // all waves' tile-t loads landed
        __builtin_amdgcn_sched_barrier(0);       // pin: nothing floats above barrier
        if (t + NBUF - 1 < nt) {
            int nb = cur + NBUF - 1; if (nb >= NBUF) nb -= NBUF;
            stage(nb, (t + NBUF - 1) << 5);      // writes buf[(t-1)%NBUF]
        }
        bf16x8v bfr[4], afr[MI];
#pragma unroll
        for (int j = 0; j < 4; ++j)
            bfr[j] = *(const bf16x8v*)&Bs[cur][(wn + j * 16 + lrow) * 32 + xq * 8];
#pragma unroll
        for (int i = 0; i < MI; ++i)
            afr[i] = *(const bf16x8v*)&As[cur][(wm + i * 16 + lrow) * 32 + xq * 8];
#pragma unroll
        for (int i = 0; i < MI; ++i)
#pragma unroll
            for (int j = 0; j < 4; ++j)
                acc[i][j] = __builtin_amdgcn_mfma_f32_16x16x32_bf16(afr[i], bfr[j], acc[i][j], 0, 0, 0);
        cur = (cur + 1 == NBUF) ? 0 : cur + 1;
    }

    const bool f32 = (*dflag != 0);
    const void* bias = hiz ? bias2 : bias1;
    if (EPI != 3) {
        bf16* O = (bf16*)(hiz ? out2 : out1) + (long)zl * (hiz ? oB2 : oB1);
#pragma unroll
        for (int i = 0; i < MI; ++i) {
            int row0 = m0 + wm + i * 16 + quad * 4;
            float rb[4] = {0.f, 0.f, 0.f, 0.f};
            if (EPI == 1 || EPI == 2) {
#pragma unroll
                for (int r = 0; r < 4; ++r) rb[r] = load1_any(bias, row0 + r, f32);
            }
#pragma unroll
            for (int j = 0; j < 4; ++j) {
                int col = n0 + wn + j * 16 + lrow;
#pragma unroll
                for (int r = 0; r < 4; ++r) {
                    float vv = acc[i][j][r];
                    if (EPI == 1) vv += rb[r];
                    if (EPI == 2) vv = vv * scale + rb[r];
                    O[(long)(row0 + r) * ldO + col] = __float2bfloat16(vv);
                }
            }
        }
    } else {
        float* O = (float*)(hiz ? out2 : out1);
        const void* res = hiz ? res2 : res1;
        const long ob  = (long)(zl + bofs) * (hiz ? oB2 : oB1);
        const long rbb = (long)(zl + bofs) * rBatch;
#pragma unroll
        for (int i = 0; i < MI; ++i) {
            int row0 = m0 + wm + i * 16 + quad * 4;
#pragma unroll
            for (int j = 0; j < 4; ++j) {
                int col = n0 + wn + j * 16 + lrow;
#pragma unroll
                for (int r = 0; r < 4; ++r) {
                    float rv = load1_any(res, rbb + (long)(row0 + r) * ldO + col, f32);
                    O[ob + (long)(row0 + r) * ldO + col] = acc[i][j][r] + rv;
                }
            }
        }
    }
}

// ---------- LayerNorm + relayout: XV rows 0-255 [256][gN] -> [(z,c)][1024] ----
__global__ __launch_bounds__(256)
void layernorm_kernel(const bf16* __restrict__ src, bf16* __restrict__ dst,
                      const void* __restrict__ g, const void* __restrict__ beta,
                      int gN, const int* __restrict__ dflag) {
    const bool f32 = (*dflag != 0);
    const int zc = blockIdx.x;          // z*256 + c
    const int zz = zc >> 8, c = zc & 255;
    const bf16* p = src + (long)c * gN + (long)zz * 1024;
    bf16* q = dst + (long)zc * 1024;
    const int tid = threadIdx.x;
    float4 v = loadbf4(p + tid * 4);
    float s  = v.x + v.y + v.z + v.w;
    float ss = v.x * v.x + v.y * v.y + v.z * v.z + v.w * v.w;
#pragma unroll
    for (int off = 32; off > 0; off >>= 1) {
        s  += __shfl_down(s, off);
        ss += __shfl_down(ss, off);
    }
    __shared__ float sh[8];
    __shared__ float sh_mu, sh_rs;
    if ((tid & 63) == 0) { sh[tid >> 6] = s; sh[4 + (tid >> 6)] = ss; }
    __syncthreads();
    if (tid == 0) {
        float S  = sh[0] + sh[1] + sh[2] + sh[3];
        float SS = sh[4] + sh[5] + sh[6] + sh[7];
        float mu = S * (1.0f / 1024.0f);
        float var = SS * (1.0f / 1024.0f) - mu * mu;
        sh_mu = mu;
        sh_rs = rsqrtf(fmaxf(var, 0.0f) + 1e-5f);
    }
    __syncthreads();
    float mu = sh_mu, rs = sh_rs;
    float gx = load1_any(g, tid * 4 + 0, f32), gy = load1_any(g, tid * 4 + 1, f32);
    float gz = load1_any(g, tid * 4 + 2, f32), gw = load1_any(g, tid * 4 + 3, f32);
    float bx = load1_any(beta, tid * 4 + 0, f32), by = load1_any(beta, tid * 4 + 1, f32);
    float bz = load1_any(beta, tid * 4 + 2, f32), bw = load1_any(beta, tid * 4 + 3, f32);
    store_bf4(q + tid * 4,
              (v.x - mu) * rs * gx + bx, (v.y - mu) * rs * gy + by,
              (v.z - mu) * rs * gz + bz, (v.w - mu) * rs * gw + bw);
}

// ---------- host ---------------------------------------------------------------
extern "C" void kernel_launch(void* const* d_in, const int* in_sizes, int n_in,
                              void* d_out, int out_size, void* d_ws, size_t ws_size,
                              hipStream_t stream) {
    const void* x_spa  = d_in[0];
    const void* x_freq = d_in[1];
    const void* w_cdc  = d_in[2];
    const void* b_cdc  = d_in[3];
    const void* w_sv   = d_in[4];
    const void* b_sv   = d_in[5];
    const void* w_fv   = d_in[6];
    const void* b_fv   = d_in[7];
    const void* ln_w   = d_in[8];
    const void* ln_b   = d_in[9];
    const void* w_qk   = d_in[10];
    const void* w_spa  = d_in[11];
    const void* b_spa  = d_in[12];
    const void* w_frq  = d_in[13];
    const void* b_frq  = d_in[14];
    float* out = (float*)d_out;          // fp32 output

    const int B = 16, C = 256;
    const long XB = 262144;              // 256*1024 elems
    const long PB = 1048576;             // 1024*1024 elems

    // header: dflag[0..1] at offset 0, bcat fp32[768] at offset 1024
    int*   dflag = (int*)d_ws;
    float* bcat  = (float*)((char*)d_ws + 1024);
    bf16*  wb    = (bf16*)((char*)d_ws + 4096);
    bf16* w_cdc_b = wb;                       // 131072  (256 x 512)
    bf16* w_sv_b  = w_cdc_b + 131072;         // 65536   (256 x 256)
    bf16* w_fv_b  = w_sv_b  + 65536;          // 65536
    bf16* w_qk_b  = w_fv_b  + 65536;          // 2097152 (lo 1M | hi 1M -> W1s)
    bf16* w_spa_b = w_qk_b  + 2097152;        // 1048576
    bf16* w_frq_b = w_spa_b + 1048576;        // 1048576
    bf16* w_qk_hiT= w_frq_b + 1048576;        // 1048576 (w_qk_hi^T copy)
    bf16* W1f     = w_qk_hiT + 1048576;       // 1048576 (w_frq @ w_qk_hi)
    bf16* Wleft   = W1f + 1048576;            // 393216  (768 x 512)
    bf16* pb      = Wleft + 393216;

    const size_t fixedB = 4096 + 6946816ull * 2;     // 13,897,728
    const size_t perB   = 8921088ull;                // 9*XB*2 + 2*PB*2 + 8192
    size_t avail = (ws_size > fixedB) ? (ws_size - fixedB) : 0;
    long gmax = (long)(avail / perB);
    const bool wsOK = (gmax >= 1);
    int G = wsOK ? (int)(gmax > 16 ? 16 : gmax) : 1;

    bf16* xT    = pb;                      // [2g][1024][256]  (spa z<g | frq)
    bf16* XV    = xT  + 2L * G * XB;       // [768][gN]: xlnF 0-255 | vb 256-767
    bf16* xln2  = XV  + 3L * G * XB;       // [(z,c)][1024]  post-LN
    bf16* qTT   = xln2 + (long)G * XB;     // [3][1024][g*256]: qT | TTs | TTf
    bf16* attpT = qTT + 3L * G * XB;       // [2g][1024][1024] scores^T -> E

    dim3 blk(256);
    detect_kernel<<<dim3(1), dim3(1024), 0, stream>>>((const unsigned short*)x_spa, dflag);

    if (!wsOK) {
        float mb = (float)(ws_size >> 20);
        diag_kernel<<<dim3(1), dim3(64), 0, stream>>>(out, 1000.0f * (mb + 1.0f));
        return;
    }

    // ---- setup: weights->bf16 + Wleft + bcat (one dispatch), w_qk_hi^T, W1 GEMM
    convert6_kernel<<<dim3(4352), blk, 0, stream>>>(
        w_cdc, w_sv, w_fv, w_qk, w_spa, w_frq, b_cdc, b_sv, b_fv,
        wb, Wleft, bcat, dflag);
    xpose_w_kernel<<<dim3(16, 16), blk, 0, stream>>>(w_qk_b + 1048576, w_qk_hiT);
    // W1s overwrites w_qk_hi slot (dead after transpose); W1f separate.
    mfma_nt<4, 0, 5><<<dim3(8, 8, 2), blk, 0, stream>>>(
        w_spa_b, w_frq_b, 0, 0, 1024, 1024,
        w_qk_hiT, w_qk_hiT, 0, 0, 1024, 1024, 1024, 0,
        w_qk_b + 1048576, W1f, 0, 0, 1024, 1024,
        1024, 1.0f, nullptr, nullptr, nullptr, nullptr, 0, 0, 1, dflag);

    for (int b0 = 0; b0 < B; b0 += G) {
        int g = (B - b0 < G) ? (B - b0) : G;
        const int gN = g * 1024;
        bf16* vb = XV + 256L * gN;

        // x_spa/x_freq -> xT (bf16, [(z,n)][ch])
        xpose_conv_kernel<<<dim3(16, 4, 2 * g), blk, 0, stream>>>(
            x_spa, x_freq, xT, b0, g, dflag);

        // XV[768][gN] = Wleft @ cat_k(x_spa,x_freq) + bcat  (K split at 256)
        // rows 0-255: pre-LN xln (c-major); 256-511: v_spa; 512-767: v_frq
        mfma_nt<4, 1, 5><<<dim3(8 * g, 6, 1), blk, 0, stream>>>(
            Wleft, Wleft, 0, 0, 512, 512,
            xT, xT, 0, 0, 256, 256, 256, (long)g * XB,
            XV, XV, 0, 0, gN, gN,
            512, 1.0f, bcat, bcat, nullptr, nullptr, 0, 0, 1, dflag + 1);

        // LN over n (1024) + relayout -> xln2[(z,c)][1024]
        layernorm_kernel<<<dim3(g * C), blk, 0, stream>>>(XV, xln2, ln_w, ln_b, gN, dflag);

        // qTT[3][1024][g*256] = [w_qk_lo; W1s; W1f] . xln2  (batched A via aB=1M)
        mfma_nt<4, 0, 5><<<dim3(2 * g, 8, 3), blk, 0, stream>>>(
            w_qk_b, W1f, 1048576, 0, 1024, 1024,
            xln2, xln2, 0, 0, 1024, 1024, 1024, 0,
            qTT, qTT + 2L * g * XB, (long)g * XB, 0, g * 256, g * 256,
            1024, 1.0f, nullptr, nullptr, nullptr, nullptr, 0, 0, 2, dflag);

        // attpT[side][z][j][n] = scale*(TT_side[j] . qT[n] over c) + bias[j]
        mfma_nt<4, 2, 3><<<dim3(8, 8, 2 * g), blk, 0, stream>>>(
            qTT + (long)g * XB, qTT + 2L * g * XB, 256, 256, g * 256, g * 256,
            qTT, qTT, 256, 256, g * 256, g * 256, 256, 0,
            attpT, attpT + (long)g * PB, PB, PB, 1024, 1024,
            256, 0.03125f, b_spa, b_frq, nullptr, nullptr, 0, 0, g, dflag);

        // column softmax + fused v-scale: attpT <- exp(attpT - colmax);
        // vb[side][c][zn] *= 1/colsum
        smnorm_kernel<<<dim3(16, 2 * g), blk, 0, stream>>>(attpT, vb, gN, g);

        // out[z][c][j] = sum_n vb[c][(z,n)] E[j][n] + x   (fp32)
        mfma_nt<4, 3, 5><<<dim3(8, 2, 2 * g), blk, 0, stream>>>(
            vb, vb + 256L * gN, 1024, 1024, gN, gN,
            attpT, attpT + (long)g * PB, PB, PB, 1024, 1024, 1024, 0,
            out, out + 4194304, XB, XB, 1024, 1024,
            1024, 1.0f, nullptr, nullptr, x_spa, x_freq, XB, b0, g, dflag);
    }
}

// Round 11
// 336.859 us; speedup vs baseline: 1.0937x; 1.0937x over previous
//
#include <hip/hip_runtime.h>
#include <hip/hip_bf16.h>

typedef __hip_bfloat16 bf16;
typedef __attribute__((ext_vector_type(8))) short bf16x8v;  // 8 bf16 = 4 VGPRs
typedef __attribute__((ext_vector_type(4))) float f32x4v;   // MFMA accumulator

// ---------- helpers -----------------------------------------------------------
__device__ __forceinline__ float bfbits2f(unsigned short h) {
    union { unsigned int u; float f; } v; v.u = ((unsigned int)h) << 16; return v.f;
}
__device__ __forceinline__ unsigned short f2bfbits(float f) {
    bf16 h = __float2bfloat16(f);
    unsigned short s;
    __builtin_memcpy(&s, &h, 2);
    return s;
}
__device__ __forceinline__ float load1_any(const void* p, long idx, bool f32) {
    if (f32) return ((const float*)p)[idx];
    return bfbits2f(((const unsigned short*)p)[idx]);
}
__device__ __forceinline__ float4 loadbf4(const bf16* p) {
    ushort4 u = *reinterpret_cast<const ushort4*>(p);
    return make_float4(bfbits2f(u.x), bfbits2f(u.y), bfbits2f(u.z), bfbits2f(u.w));
}
__device__ __forceinline__ void store_bf4(bf16* p, float a, float b, float c, float d) {
    ushort4 o;
    o.x = f2bfbits(a); o.y = f2bfbits(b); o.z = f2bfbits(c); o.w = f2bfbits(d);
    *reinterpret_cast<ushort4*>(p) = o;
}
// async global->LDS, 16B per lane; LDS dest = wave-uniform base + lane*16
__device__ __forceinline__ void gl16(const void* g, void* l) {
    __builtin_amdgcn_global_load_lds(
        (const __attribute__((address_space(1))) unsigned int*)g,
        (__attribute__((address_space(3))) unsigned int*)l, 16, 0, 0);
}
// ordered-uint encoding for fp32 atomicMax (monotonic in float order)
#define CMAX_INIT 0x00800000u   /* encode(-3.4e38f) */

// ---------- input dtype detection (flag[0]=1: raw inputs are fp32) ------------
__global__ __launch_bounds__(1024)
void detect_kernel(const unsigned short* __restrict__ x, int* __restrict__ flag) {
    const int tid = threadIdx.x;
    int zc = 0, hc = 0;
    const uint4* xv = (const uint4*)x;
#pragma unroll
    for (int p = 0; p < 16; ++p) {
        uint4 v = xv[p * 1024 + tid];
        unsigned s0 = v.x & 0xFFFFu, s1 = v.y & 0xFFFFu;
        unsigned s2 = v.z & 0xFFFFu, s3 = v.w & 0xFFFFu;
        zc += (int)(s0 == 0) + (int)(s1 == 0) + (int)(s2 == 0) + (int)(s3 == 0);
        hc += (int)(((s0 >> 7) & 0xFFu) >= 0x90u) + (int)(((s1 >> 7) & 0xFFu) >= 0x90u)
            + (int)(((s2 >> 7) & 0xFFu) >= 0x90u) + (int)(((s3 >> 7) & 0xFFu) >= 0x90u);
    }
#pragma unroll
    for (int off = 32; off > 0; off >>= 1) {
        zc += __shfl_down(zc, off);
        hc += __shfl_down(hc, off);
    }
    __shared__ int rz[16], rh[16];
    if ((tid & 63) == 0) { rz[tid >> 6] = zc; rh[tid >> 6] = hc; }
    __syncthreads();
    if (tid == 0) {
        int Z = 0, H = 0;
#pragma unroll
        for (int i = 0; i < 16; ++i) { Z += rz[i]; H += rh[i]; }
        flag[0] = (Z > 60000 || H > 256) ? 1 : 0;
        flag[1] = 1;
    }
}

__global__ void diag_kernel(float* __restrict__ out, float val) {
    if (threadIdx.x == 0) out[0] = val;
}

// ---------- fused setup convert: 6 weights + Wleft + bcat in one dispatch -----
__global__ __launch_bounds__(256)
void convert6_kernel(const void* __restrict__ s0, const void* __restrict__ s1,
                     const void* __restrict__ s2, const void* __restrict__ s3,
                     const void* __restrict__ s4, const void* __restrict__ s5,
                     const void* __restrict__ b0, const void* __restrict__ b1,
                     const void* __restrict__ b2,
                     bf16* __restrict__ dst, bf16* __restrict__ wl,
                     float* __restrict__ bc, const int* __restrict__ dflag) {
    const bool f32 = (*dflag != 0);
    for (long i = (long)blockIdx.x * 256 + threadIdx.x; i < 4850432;
         i += (long)gridDim.x * 256) {
        if (i < 4456448) {
            const void* s; long o;
            if (i < 131072)       { s = s0; o = i; }
            else if (i < 196608)  { s = s1; o = i - 131072; }
            else if (i < 262144)  { s = s2; o = i - 196608; }
            else if (i < 2359296) { s = s3; o = i - 262144; }
            else if (i < 3407872) { s = s4; o = i - 2359296; }
            else                  { s = s5; o = i - 3407872; }
            dst[i] = __float2bfloat16(load1_any(s, o, f32));
        } else if (i < 4849664) {
            long j = i - 4456448;
            int r = (int)(j >> 9), c = (int)(j & 511);
            float v = 0.f;
            if (r < 256) v = load1_any(s0, r * 512 + c, f32);
            else if (r < 512) { if (c < 256) v = load1_any(s1, (r - 256) * 256 + c, f32); }
            else              { if (c >= 256) v = load1_any(s2, (r - 512) * 256 + (c - 256), f32); }
            wl[j] = __float2bfloat16(v);
        } else {
            long j = i - 4849664;
            float v = (j < 256) ? load1_any(b0, j, f32)
                    : (j < 512) ? load1_any(b1, j - 256, f32)
                                : load1_any(b2, j - 512, f32);
            bc[j] = v;
        }
    }
}

// ---------- bf16 transpose 1024x1024 (for w_qk_hi) ----------------------------
__global__ __launch_bounds__(256)
void xpose_w_kernel(const bf16* __restrict__ src, bf16* __restrict__ dst) {
    __shared__ float t[64][65];
    const int c0 = blockIdx.x * 64, r0 = blockIdx.y * 64;
    const int tid = threadIdx.x;
#pragma unroll
    for (int p = 0; p < 16; ++p) {
        int e = tid + p * 256; int r = e >> 6, c = e & 63;
        t[r][c] = __bfloat162float(src[(long)(r0 + r) * 1024 + c0 + c]);
    }
    __syncthreads();
#pragma unroll
    for (int p = 0; p < 16; ++p) {
        int e = tid + p * 256; int r = e >> 6, c = e & 63;
        dst[(long)(c0 + r) * 1024 + r0 + c] = __float2bfloat16(t[c][r]);
    }
}

// ---------- transpose+convert: x[bg][256][1024] raw -> xT[z][1024][256] bf16 --
// Also: block (0,0,z) initializes colmax[z][0..1023] to the -inf key.
__global__ __launch_bounds__(256)
void xpose_conv_kernel(const void* __restrict__ x1, const void* __restrict__ x2,
                       bf16* __restrict__ dst, unsigned* __restrict__ colmax,
                       int bofs, int zsplit, const int* __restrict__ dflag) {
    const bool f32 = (*dflag != 0);
    __shared__ float t[64][65];
    const int ch0 = blockIdx.y * 64, n0 = blockIdx.x * 64, z = blockIdx.z;
    const bool hiz = (z >= zsplit);
    const int zl = hiz ? z - zsplit : z;
    const void* x = hiz ? x2 : x1;
    const long sb = (long)(zl + bofs) * 262144, db = (long)z * 262144;
    const int tid = threadIdx.x;
    if (blockIdx.x == 0 && blockIdx.y == 0) {
        uint4* ci = (uint4*)(colmax + (long)z * 1024) + tid;
        *ci = make_uint4(CMAX_INIT, CMAX_INIT, CMAX_INIT, CMAX_INIT);
    }
    if (f32) {
        const float* xf = (const float*)x;
#pragma unroll
        for (int p = 0; p < 4; ++p) {
            int e = tid + p * 256; int sch = e >> 4, sn = (e & 15) * 4;
            float4 v = *(const float4*)(xf + sb + (long)(ch0 + sch) * 1024 + n0 + sn);
            t[sch][sn] = v.x; t[sch][sn + 1] = v.y;
            t[sch][sn + 2] = v.z; t[sch][sn + 3] = v.w;
        }
    } else {
#pragma unroll
        for (int p = 0; p < 16; ++p) {
            int e = tid + p * 256; int sch = e >> 6, sn = e & 63;
            t[sch][sn] = bfbits2f(((const unsigned short*)x)[sb + (long)(ch0 + sch) * 1024 + n0 + sn]);
        }
    }
    __syncthreads();
#pragma unroll
    for (int p = 0; p < 16; ++p) {
        int e = tid + p * 256; int dn = e >> 6, dch = e & 63;
        dst[db + (long)(n0 + dn) * 256 + ch0 + dch] = __float2bfloat16(t[dch][dn]);
    }
}

// ---------- single-pass column softmax + fused v-scale ------------------------
// colmax[z'][n] holds ordered-uint keys of per-column fp32 maxima (from attp
// epilogue).  X <- exp(X - M); vb[side][c][zn] *= 1/colsum.
__global__ __launch_bounds__(256)
void smnorm_kernel(bf16* __restrict__ X, bf16* __restrict__ vb,
                   const unsigned* __restrict__ colmax, int gN, int gq) {
    const int tid = threadIdx.x;
    const int cg = tid & 7;            // col group (8 cols, 16B)
    const int js = tid >> 3;           // row slice (0..31)
    const int n0 = blockIdx.x * 64;
    const long zb = (long)blockIdx.y * 1048576;
    unsigned short* Xp = (unsigned short*)X + zb + n0 + cg * 8;
    const unsigned* cm = colmax + (long)blockIdx.y * 1024 + n0 + cg * 8;

    float M8[8], s8[8];
#pragma unroll
    for (int q = 0; q < 8; ++q) {
        unsigned k = cm[q];
        unsigned b = (k & 0x80000000u) ? (k & 0x7fffffffu) : ~k;
        M8[q] = __uint_as_float(b);
        s8[q] = 0.f;
    }
#pragma unroll 4
    for (int r = 0; r < 32; ++r) {
        long off = (long)(js * 32 + r) * 1024;
        bf16x8v u = *(const bf16x8v*)(Xp + off);
        bf16x8v o;
#pragma unroll
        for (int q = 0; q < 8; ++q) {
            float e = __expf(bfbits2f((unsigned short)u[q]) - M8[q]);
            s8[q] += e;
            o[q] = (short)f2bfbits(e);
        }
        *(bf16x8v*)(Xp + off) = o;
    }
    __shared__ float sh[32][8][8];
    __shared__ float Sc[64];
#pragma unroll
    for (int q = 0; q < 8; ++q) sh[js][cg][q] = s8[q];
    __syncthreads();
    if (tid < 64) {
        float ss = 0.f;
#pragma unroll 8
        for (int s = 0; s < 32; ++s) ss += sh[s][tid >> 3][tid & 7];
        Sc[tid] = 1.0f / ss;
    }
    __syncthreads();
    const int side = (blockIdx.y >= (unsigned)gq) ? 1 : 0;
    const int zl = blockIdx.y - side * gq;
    bf16* vp = vb + (long)(side * 256) * gN + (long)zl * 1024 + n0 + cg * 8;
    float is8[8];
#pragma unroll
    for (int q = 0; q < 8; ++q) is8[q] = Sc[cg * 8 + q];
#pragma unroll
    for (int rr = 0; rr < 8; ++rr) {
        long off = (long)(rr * 32 + js) * gN;
        bf16x8v u = *(bf16x8v*)(vp + off);
        bf16x8v o;
#pragma unroll
        for (int q = 0; q < 8; ++q)
            o[q] = (short)f2bfbits(bfbits2f((unsigned short)u[q]) * is8[q]);
        *(bf16x8v*)(vp + off) = o;
    }
}

// ---------- 256-thread BMx128 NT MFMA GEMM, NBUF=3 ring, counted vmcnt --------
// D[z][m][n] = sum_k A[z][m][k] * B[z][n][k]   (both k-contiguous).
// Ring: prologue stages 0,1; loop: wait vmcnt(L) -> barrier -> sched_barrier ->
// stage(t+2) -> ds_read -> MFMA (compiler schedules fine-grained lgkmcnt).
// Buffer-reuse safety: stage(t+2) writes buf[(t-1)%3]; step-(t-1) readers
// consumed all ds_reads via MFMAs before reaching barrier t.
// XCD swizzle (T1): remap flat id so each XCD owns a contiguous chunk, z slowest.
// EPI: 0 plain bf16 | 1 +bias[row] | 2 *scale+bias[row] + colmax atomics | 3 +res fp32
template <int MI, int EPI>
__global__ __launch_bounds__(256)
void mfma_nt(const bf16* __restrict__ A1, const bf16* __restrict__ A2,
             long aB1, long aB2, int ldA1, int ldA2,
             const bf16* __restrict__ B1, const bf16* __restrict__ B2,
             long bB1, long bB2, int ldB1, int ldB2,
             int ksplit, long kOff2,
             void* __restrict__ out1, void* __restrict__ out2,
             long oB1, long oB2, int ldO1, int ldO2,
             int K, float scale,
             const void* __restrict__ bias1, const void* __restrict__ bias2,
             const void* __restrict__ res1, const void* __restrict__ res2,
             long rBatch, int bofs, int zsplit,
             const int* __restrict__ dflag) {
    constexpr int BM = MI * 32;
    __shared__ short As[3][BM * 32];
    __shared__ short Bs[3][4096];
    const int tid  = threadIdx.x;
    const int lane = tid & 63, wave = tid >> 6;
    const int quad = lane >> 4, lrow = lane & 15;
    const int wm = (wave >> 1) * (MI * 16), wn = (wave & 1) * 64;

    // ---- XCD-aware block swizzle (bijective when ntot % 8 == 0) ----
    int bx = blockIdx.x, by = blockIdx.y, bz = blockIdx.z;
    {
        const int gx = gridDim.x, gy = gridDim.y;
        const int gxy = gx * gy;
        const int ntot = gxy * gridDim.z;
        if ((ntot & 7) == 0) {
            int flat = bx + gx * (by + gy * bz);
            int w = (flat & 7) * (ntot >> 3) + (flat >> 3);
            bz = w / gxy;
            int rem = w - bz * gxy;
            by = rem / gx;
            bx = rem - by * gx;
        }
    }
    const int z  = bz;
    const bool hiz = (z >= zsplit);
    const int zl = hiz ? z - zsplit : z;
    const int n0 = bx * 128, m0 = by * BM;
    const int ldA = hiz ? ldA2 : ldA1, ldB = hiz ? ldB2 : ldB1;
    const int ldO = hiz ? ldO2 : ldO1;
    const int srow = tid >> 2, sseg = tid & 3;
    const int sl = sseg ^ ((srow >> 1) & 3);        // staging: swizzled seg
    const int xq = quad ^ ((lrow >> 1) & 3);        // read: physical seg

    const bf16* Ab = (hiz ? A2 : A1) + (long)zl * (hiz ? aB2 : aB1);
    const bf16* Bb = (hiz ? B2 : B1) + (long)zl * (hiz ? bB2 : bB1);

    auto stage = [&](int buf, int k0) {
        const bf16* asrc = Ab + (long)k0;
        const bf16* bsrc = Bb + ((k0 < ksplit) ? (long)k0 : (long)(k0 - ksplit) + kOff2);
#pragma unroll
        for (int p = 0; p < MI / 2; ++p)
            gl16(asrc + (long)(m0 + p * 64 + srow) * ldA + sl * 8,
                 &As[buf][p * 2048 + wave * 512]);
        gl16(bsrc + (long)(n0 + srow) * ldB + sl * 8, &Bs[buf][wave * 512]);
        gl16(bsrc + (long)(n0 + 64 + srow) * ldB + sl * 8, &Bs[buf][2048 + wave * 512]);
    };

    f32x4v acc[MI][4] = {};
    const int nt = K >> 5;
    stage(0, 0);
    if (nt > 1) stage(1, 32);

    int cur = 0;
    for (int t = 0; t < nt; ++t) {
        if (t + 1 < nt) {
            if constexpr (MI == 4) asm volatile("s_waitcnt vmcnt(4)" ::: "memory");
            else                   asm volatile("s_waitcnt vmcnt(3)" ::: "memory");
        } else {
            asm volatile("s_waitcnt vmcnt(0)" ::: "memory");
        }
        __builtin_amdgcn_s_barrier();            // all waves' tile-t loads landed
        __builtin_amdgcn_sched_barrier(0);       // pin: nothing floats above barrier
        if (t + 2 < nt) {
            int nb = cur + 2; if (nb >= 3) nb -= 3;
            stage(nb, (t + 2) << 5);             // writes buf[(t-1)%3]
        }
        bf16x8v bfr[4], afr[MI];
#pragma unroll
        for (int j = 0; j < 4; ++j)
            bfr[j] = *(const bf16x8v*)&Bs[cur][(wn + j * 16 + lrow) * 32 + xq * 8];
#pragma unroll
        for (int i = 0; i < MI; ++i)
            afr[i] = *(const bf16x8v*)&As[cur][(wm + i * 16 + lrow) * 32 + xq * 8];
        __builtin_amdgcn_s_setprio(1);
#pragma unroll
        for (int i = 0; i < MI; ++i)
#pragma unroll
            for (int j = 0; j < 4; ++j)
                acc[i][j] = __builtin_amdgcn_mfma_f32_16x16x32_bf16(afr[i], bfr[j], acc[i][j], 0, 0, 0);
        __builtin_amdgcn_s_setprio(0);
        cur = (cur == 2) ? 0 : cur + 1;
    }

    const bool f32 = (*dflag != 0);
    const void* bias = hiz ? bias2 : bias1;
    if (EPI != 3) {
        bf16* O = (bf16*)(hiz ? out2 : out1) + (long)zl * (hiz ? oB2 : oB1);
        float colm[4] = {-3.4e38f, -3.4e38f, -3.4e38f, -3.4e38f};
#pragma unroll
        for (int i = 0; i < MI; ++i) {
            int row0 = m0 + wm + i * 16 + quad * 4;
            float rb[4] = {0.f, 0.f, 0.f, 0.f};
            if (EPI == 1 || EPI == 2) {
#pragma unroll
                for (int r = 0; r < 4; ++r) rb[r] = load1_any(bias, row0 + r, f32);
            }
#pragma unroll
            for (int j = 0; j < 4; ++j) {
                int col = n0 + wn + j * 16 + lrow;
#pragma unroll
                for (int r = 0; r < 4; ++r) {
                    float vv = acc[i][j][r];
                    if (EPI == 1) vv += rb[r];
                    if (EPI == 2) { vv = vv * scale + rb[r]; colm[j] = fmaxf(colm[j], vv); }
                    O[(long)(row0 + r) * ldO + col] = __float2bfloat16(vv);
                }
            }
        }
        if constexpr (EPI == 2) {
            // per-column max of this 128x128 tile -> global ordered-uint atomicMax
            __shared__ float smx[2][128];
#pragma unroll
            for (int off = 16; off < 64; off <<= 1)
#pragma unroll
                for (int j = 0; j < 4; ++j)
                    colm[j] = fmaxf(colm[j], __shfl_xor(colm[j], off));
            if (quad == 0) {
#pragma unroll
                for (int j = 0; j < 4; ++j)
                    smx[wave >> 1][wn + j * 16 + lrow] = colm[j];
            }
            __syncthreads();
            if (tid < 128) {
                float M = fmaxf(smx[0][tid], smx[1][tid]);
                unsigned b = __float_as_uint(M);
                unsigned key = (b & 0x80000000u) ? ~b : (b | 0x80000000u);
                unsigned* cmp = (unsigned*)(hiz ? res2 : res1) + (long)zl * rBatch + n0 + tid;
                atomicMax(cmp, key);
            }
        }
    } else {
        float* O = (float*)(hiz ? out2 : out1);
        const void* res = hiz ? res2 : res1;
        const long ob  = (long)(zl + bofs) * (hiz ? oB2 : oB1);
        const long rbb = (long)(zl + bofs) * rBatch;
#pragma unroll
        for (int i = 0; i < MI; ++i) {
            int row0 = m0 + wm + i * 16 + quad * 4;
#pragma unroll
            for (int j = 0; j < 4; ++j) {
                int col = n0 + wn + j * 16 + lrow;
#pragma unroll
                for (int r = 0; r < 4; ++r) {
                    float rv = load1_any(res, rbb + (long)(row0 + r) * ldO + col, f32);
                    O[ob + (long)(row0 + r) * ldO + col] = acc[i][j][r] + rv;
                }
            }
        }
    }
}

// ---------- LayerNorm + relayout: XV rows 0-255 [256][gN] -> [(z,c)][1024] ----
__global__ __launch_bounds__(256)
void layernorm_kernel(const bf16* __restrict__ src, bf16* __restrict__ dst,
                      const void* __restrict__ g, const void* __restrict__ beta,
                      int gN, const int* __restrict__ dflag) {
    const bool f32 = (*dflag != 0);
    const int zc = blockIdx.x;          // z*256 + c
    const int zz = zc >> 8, c = zc & 255;
    const bf16* p = src + (long)c * gN + (long)zz * 1024;
    bf16* q = dst + (long)zc * 1024;
    const int tid = threadIdx.x;
    float4 v = loadbf4(p + tid * 4);
    float s  = v.x + v.y + v.z + v.w;
    float ss = v.x * v.x + v.y * v.y + v.z * v.z + v.w * v.w;
#pragma unroll
    for (int off = 32; off > 0; off >>= 1) {
        s  += __shfl_down(s, off);
        ss += __shfl_down(ss, off);
    }
    __shared__ float sh[8];
    __shared__ float sh_mu, sh_rs;
    if ((tid & 63) == 0) { sh[tid >> 6] = s; sh[4 + (tid >> 6)] = ss; }
    __syncthreads();
    if (tid == 0) {
        float S  = sh[0] + sh[1] + sh[2] + sh[3];
        float SS = sh[4] + sh[5] + sh[6] + sh[7];
        float mu = S * (1.0f / 1024.0f);
        float var = SS * (1.0f / 1024.0f) - mu * mu;
        sh_mu = mu;
        sh_rs = rsqrtf(fmaxf(var, 0.0f) + 1e-5f);
    }
    __syncthreads();
    float mu = sh_mu, rs = sh_rs;
    float gx = load1_any(g, tid * 4 + 0, f32), gy = load1_any(g, tid * 4 + 1, f32);
    float gz = load1_any(g, tid * 4 + 2, f32), gw = load1_any(g, tid * 4 + 3, f32);
    float bx = load1_any(beta, tid * 4 + 0, f32), by = load1_any(beta, tid * 4 + 1, f32);
    float bz = load1_any(beta, tid * 4 + 2, f32), bw = load1_any(beta, tid * 4 + 3, f32);
    store_bf4(q + tid * 4,
              (v.x - mu) * rs * gx + bx, (v.y - mu) * rs * gy + by,
              (v.z - mu) * rs * gz + bz, (v.w - mu) * rs * gw + bw);
}

// ---------- host ---------------------------------------------------------------
extern "C" void kernel_launch(void* const* d_in, const int* in_sizes, int n_in,
                              void* d_out, int out_size, void* d_ws, size_t ws_size,
                              hipStream_t stream) {
    const void* x_spa  = d_in[0];
    const void* x_freq = d_in[1];
    const void* w_cdc  = d_in[2];
    const void* b_cdc  = d_in[3];
    const void* w_sv   = d_in[4];
    const void* b_sv   = d_in[5];
    const void* w_fv   = d_in[6];
    const void* b_fv   = d_in[7];
    const void* ln_w   = d_in[8];
    const void* ln_b   = d_in[9];
    const void* w_qk   = d_in[10];
    const void* w_spa  = d_in[11];
    const void* b_spa  = d_in[12];
    const void* w_frq  = d_in[13];
    const void* b_frq  = d_in[14];
    float* out = (float*)d_out;          // fp32 output

    const int B = 16, C = 256;
    const long XB = 262144;              // 256*1024 elems
    const long PB = 1048576;             // 1024*1024 elems

    // header: dflag[0..1] at offset 0, bcat fp32[768] at offset 1024
    int*   dflag = (int*)d_ws;
    float* bcat  = (float*)((char*)d_ws + 1024);
    bf16*  wb    = (bf16*)((char*)d_ws + 4096);
    bf16* w_cdc_b = wb;                       // 131072  (256 x 512)
    bf16* w_sv_b  = w_cdc_b + 131072;         // 65536
    bf16* w_fv_b  = w_sv_b  + 65536;          // 65536
    bf16* w_qk_b  = w_fv_b  + 65536;          // 2097152 (lo 1M | hi 1M -> W1s)
    bf16* w_spa_b = w_qk_b  + 2097152;        // 1048576
    bf16* w_frq_b = w_spa_b + 1048576;        // 1048576
    bf16* w_qk_hiT= w_frq_b + 1048576;        // 1048576 (w_qk_hi^T copy)
    bf16* W1f     = w_qk_hiT + 1048576;       // 1048576 (w_frq @ w_qk_hi)
    bf16* Wleft   = W1f + 1048576;            // 393216  (768 x 512)
    bf16* pb      = Wleft + 393216;

    const size_t fixedB = 4096 + 6946816ull * 2;     // 13,897,728
    const size_t perB   = 8921088ull;                // 9*XB*2 + 2*PB*2 + 8192
    size_t avail = (ws_size > fixedB) ? (ws_size - fixedB) : 0;
    long gmax = (long)(avail / perB);
    const bool wsOK = (gmax >= 1);
    int G = wsOK ? (int)(gmax > 16 ? 16 : gmax) : 1;

    bf16* xT    = pb;                      // [2g][1024][256]  (spa z<g | frq)
    bf16* XV    = xT  + 2L * G * XB;       // [768][gN]: xlnF 0-255 | vb 256-767
    bf16* xln2  = XV  + 3L * G * XB;       // [(z,c)][1024]  post-LN
    bf16* qTT   = xln2 + (long)G * XB;     // [3][1024][g*256]: qT | TTs | TTf
    bf16* attpT = qTT + 3L * G * XB;       // [2g][1024][1024] scores^T -> E
    unsigned* colmax = (unsigned*)(attpT + 2L * G * PB);   // [2g][1024] keys

    dim3 blk(256);
    detect_kernel<<<dim3(1), dim3(1024), 0, stream>>>((const unsigned short*)x_spa, dflag);

    if (!wsOK) {
        float mb = (float)(ws_size >> 20);
        diag_kernel<<<dim3(1), dim3(64), 0, stream>>>(out, 1000.0f * (mb + 1.0f));
        return;
    }

    // ---- setup: weights->bf16 + Wleft + bcat (one dispatch), w_qk_hi^T, W1 GEMM
    convert6_kernel<<<dim3(4352), blk, 0, stream>>>(
        w_cdc, w_sv, w_fv, w_qk, w_spa, w_frq, b_cdc, b_sv, b_fv,
        wb, Wleft, bcat, dflag);
    xpose_w_kernel<<<dim3(16, 16), blk, 0, stream>>>(w_qk_b + 1048576, w_qk_hiT);
    // W1s overwrites w_qk_hi slot (dead after transpose); W1f separate.
    mfma_nt<4, 0><<<dim3(8, 8, 2), blk, 0, stream>>>(
        w_spa_b, w_frq_b, 0, 0, 1024, 1024,
        w_qk_hiT, w_qk_hiT, 0, 0, 1024, 1024, 1024, 0,
        w_qk_b + 1048576, W1f, 0, 0, 1024, 1024,
        1024, 1.0f, nullptr, nullptr, nullptr, nullptr, 0, 0, 1, dflag);

    for (int b0 = 0; b0 < B; b0 += G) {
        int g = (B - b0 < G) ? (B - b0) : G;
        const int gN = g * 1024;
        bf16* vb = XV + 256L * gN;

        // x_spa/x_freq -> xT (bf16, [(z,n)][ch]); also init colmax[2g][1024]
        xpose_conv_kernel<<<dim3(16, 4, 2 * g), blk, 0, stream>>>(
            x_spa, x_freq, xT, colmax, b0, g, dflag);

        // XV[768][gN] = Wleft @ cat_k(x_spa,x_freq) + bcat  (K split at 256)
        mfma_nt<4, 1><<<dim3(8 * g, 6, 1), blk, 0, stream>>>(
            Wleft, Wleft, 0, 0, 512, 512,
            xT, xT, 0, 0, 256, 256, 256, (long)g * XB,
            XV, XV, 0, 0, gN, gN,
            512, 1.0f, bcat, bcat, nullptr, nullptr, 0, 0, 1, dflag + 1);

        // LN over n (1024) + relayout -> xln2[(z,c)][1024]
        layernorm_kernel<<<dim3(g * C), blk, 0, stream>>>(XV, xln2, ln_w, ln_b, gN, dflag);

        // qTT[3][1024][g*256] = [w_qk_lo; W1s; W1f] . xln2
        mfma_nt<4, 0><<<dim3(2 * g, 8, 3), blk, 0, stream>>>(
            w_qk_b, W1f, 1048576, 0, 1024, 1024,
            xln2, xln2, 0, 0, 1024, 1024, 1024, 0,
            qTT, qTT + 2L * g * XB, (long)g * XB, 0, g * 256, g * 256,
            1024, 1.0f, nullptr, nullptr, nullptr, nullptr, 0, 0, 2, dflag);

        // attpT[side][z][j][n] = scale*(TT_side[j].qT[n]) + bias[j]; colmax atomics
        mfma_nt<4, 2><<<dim3(8, 8, 2 * g), blk, 0, stream>>>(
            qTT + (long)g * XB, qTT + 2L * g * XB, 256, 256, g * 256, g * 256,
            qTT, qTT, 256, 256, g * 256, g * 256, 256, 0,
            attpT, attpT + (long)g * PB, PB, PB, 1024, 1024,
            256, 0.03125f, b_spa, b_frq, colmax, colmax + (long)g * 1024,
            1024, 0, g, dflag);

        // single-pass column softmax + fused v-scale
        smnorm_kernel<<<dim3(16, 2 * g), blk, 0, stream>>>(attpT, vb, colmax, gN, g);

        // out[z][c][j] = sum_n vb[c][(z,n)] E[j][n] + x   (fp32)
        mfma_nt<4, 3><<<dim3(8, 2, 2 * g), blk, 0, stream>>>(
            vb, vb + 256L * gN, 1024, 1024, gN, gN,
            attpT, attpT + (long)g * PB, PB, PB, 1024, 1024, 1024, 0,
            out, out + 4194304, XB, XB, 1024, 1024,
            1024, 1.0f, nullptr, nullptr, x_spa, x_freq, XB, b0, g, dflag);
    }
}

// Round 13
// 334.082 us; speedup vs baseline: 1.1028x; 1.0083x over previous
//
#include <hip/hip_runtime.h>
#include <hip/hip_bf16.h>

typedef __hip_bfloat16 bf16;
typedef __attribute__((ext_vector_type(8))) short bf16x8v;  // 8 bf16 = 4 VGPRs
typedef __attribute__((ext_vector_type(4))) float f32x4v;   // MFMA accumulator

// ---------- helpers -----------------------------------------------------------
__device__ __forceinline__ float bfbits2f(unsigned short h) {
    union { unsigned int u; float f; } v; v.u = ((unsigned int)h) << 16; return v.f;
}
__device__ __forceinline__ unsigned short f2bfbits(float f) {
    bf16 h = __float2bfloat16(f);
    unsigned short s;
    __builtin_memcpy(&s, &h, 2);
    return s;
}
__device__ __forceinline__ float load1_any(const void* p, long idx, bool f32) {
    if (f32) return ((const float*)p)[idx];
    return bfbits2f(((const unsigned short*)p)[idx]);
}
__device__ __forceinline__ float4 loadbf4(const bf16* p) {
    ushort4 u = *reinterpret_cast<const ushort4*>(p);
    return make_float4(bfbits2f(u.x), bfbits2f(u.y), bfbits2f(u.z), bfbits2f(u.w));
}
__device__ __forceinline__ void store_bf4(bf16* p, float a, float b, float c, float d) {
    ushort4 o;
    o.x = f2bfbits(a); o.y = f2bfbits(b); o.z = f2bfbits(c); o.w = f2bfbits(d);
    *reinterpret_cast<ushort4*>(p) = o;
}
// async global->LDS, 16B per lane; LDS dest = wave-uniform base + lane*16
__device__ __forceinline__ void gl16(const void* g, void* l) {
    __builtin_amdgcn_global_load_lds(
        (const __attribute__((address_space(1))) unsigned int*)g,
        (__attribute__((address_space(3))) unsigned int*)l, 16, 0, 0);
}
// ordered-uint encoding for fp32 atomicMax (monotonic in float order)
#define CMAX_INIT 0x00800000u   /* encode(-3.4e38f) */

// ---------- input dtype detection (flag[0]=1: raw inputs are fp32) ------------
__global__ __launch_bounds__(1024)
void detect_kernel(const unsigned short* __restrict__ x, int* __restrict__ flag) {
    const int tid = threadIdx.x;
    int zc = 0, hc = 0;
    const uint4* xv = (const uint4*)x;
#pragma unroll
    for (int p = 0; p < 16; ++p) {
        uint4 v = xv[p * 1024 + tid];
        unsigned s0 = v.x & 0xFFFFu, s1 = v.y & 0xFFFFu;
        unsigned s2 = v.z & 0xFFFFu, s3 = v.w & 0xFFFFu;
        zc += (int)(s0 == 0) + (int)(s1 == 0) + (int)(s2 == 0) + (int)(s3 == 0);
        hc += (int)(((s0 >> 7) & 0xFFu) >= 0x90u) + (int)(((s1 >> 7) & 0xFFu) >= 0x90u)
            + (int)(((s2 >> 7) & 0xFFu) >= 0x90u) + (int)(((s3 >> 7) & 0xFFu) >= 0x90u);
    }
#pragma unroll
    for (int off = 32; off > 0; off >>= 1) {
        zc += __shfl_down(zc, off);
        hc += __shfl_down(hc, off);
    }
    __shared__ int rz[16], rh[16];
    if ((tid & 63) == 0) { rz[tid >> 6] = zc; rh[tid >> 6] = hc; }
    __syncthreads();
    if (tid == 0) {
        int Z = 0, H = 0;
#pragma unroll
        for (int i = 0; i < 16; ++i) { Z += rz[i]; H += rh[i]; }
        flag[0] = (Z > 60000 || H > 256) ? 1 : 0;
        flag[1] = 1;
    }
}

__global__ void diag_kernel(float* __restrict__ out, float val) {
    if (threadIdx.x == 0) out[0] = val;
}

// ---------- fused setup convert: 6 weights + Wleft + bcat in one dispatch -----
__global__ __launch_bounds__(256)
void convert6_kernel(const void* __restrict__ s0, const void* __restrict__ s1,
                     const void* __restrict__ s2, const void* __restrict__ s3,
                     const void* __restrict__ s4, const void* __restrict__ s5,
                     const void* __restrict__ b0, const void* __restrict__ b1,
                     const void* __restrict__ b2,
                     bf16* __restrict__ dst, bf16* __restrict__ wl,
                     float* __restrict__ bc, const int* __restrict__ dflag) {
    const bool f32 = (*dflag != 0);
    for (long i = (long)blockIdx.x * 256 + threadIdx.x; i < 4850432;
         i += (long)gridDim.x * 256) {
        if (i < 4456448) {
            const void* s; long o;
            if (i < 131072)       { s = s0; o = i; }
            else if (i < 196608)  { s = s1; o = i - 131072; }
            else if (i < 262144)  { s = s2; o = i - 196608; }
            else if (i < 2359296) { s = s3; o = i - 262144; }
            else if (i < 3407872) { s = s4; o = i - 2359296; }
            else                  { s = s5; o = i - 3407872; }
            dst[i] = __float2bfloat16(load1_any(s, o, f32));
        } else if (i < 4849664) {
            long j = i - 4456448;
            int r = (int)(j >> 9), c = (int)(j & 511);
            float v = 0.f;
            if (r < 256) v = load1_any(s0, r * 512 + c, f32);
            else if (r < 512) { if (c < 256) v = load1_any(s1, (r - 256) * 256 + c, f32); }
            else              { if (c >= 256) v = load1_any(s2, (r - 512) * 256 + (c - 256), f32); }
            wl[j] = __float2bfloat16(v);
        } else {
            long j = i - 4849664;
            float v = (j < 256) ? load1_any(b0, j, f32)
                    : (j < 512) ? load1_any(b1, j - 256, f32)
                                : load1_any(b2, j - 512, f32);
            bc[j] = v;
        }
    }
}

// ---------- bf16 transpose 1024x1024 (for w_qk_hi) ----------------------------
__global__ __launch_bounds__(256)
void xpose_w_kernel(const bf16* __restrict__ src, bf16* __restrict__ dst) {
    __shared__ float t[64][65];
    const int c0 = blockIdx.x * 64, r0 = blockIdx.y * 64;
    const int tid = threadIdx.x;
#pragma unroll
    for (int p = 0; p < 16; ++p) {
        int e = tid + p * 256; int r = e >> 6, c = e & 63;
        t[r][c] = __bfloat162float(src[(long)(r0 + r) * 1024 + c0 + c]);
    }
    __syncthreads();
#pragma unroll
    for (int p = 0; p < 16; ++p) {
        int e = tid + p * 256; int r = e >> 6, c = e & 63;
        dst[(long)(c0 + r) * 1024 + r0 + c] = __float2bfloat16(t[c][r]);
    }
}

// ---------- transpose+convert: x[bg][256][1024] raw -> xT[z][1024][256] bf16 --
// Also: block (0,0,z) initializes colmax[z][0..1023] to the -inf key.
__global__ __launch_bounds__(256)
void xpose_conv_kernel(const void* __restrict__ x1, const void* __restrict__ x2,
                       bf16* __restrict__ dst, unsigned* __restrict__ colmax,
                       int bofs, int zsplit, const int* __restrict__ dflag) {
    const bool f32 = (*dflag != 0);
    __shared__ float t[64][65];
    const int ch0 = blockIdx.y * 64, n0 = blockIdx.x * 64, z = blockIdx.z;
    const bool hiz = (z >= zsplit);
    const int zl = hiz ? z - zsplit : z;
    const void* x = hiz ? x2 : x1;
    const long sb = (long)(zl + bofs) * 262144, db = (long)z * 262144;
    const int tid = threadIdx.x;
    if (blockIdx.x == 0 && blockIdx.y == 0) {
        uint4* ci = (uint4*)(colmax + (long)z * 1024) + tid;
        *ci = make_uint4(CMAX_INIT, CMAX_INIT, CMAX_INIT, CMAX_INIT);
    }
    if (f32) {
        const float* xf = (const float*)x;
#pragma unroll
        for (int p = 0; p < 4; ++p) {
            int e = tid + p * 256; int sch = e >> 4, sn = (e & 15) * 4;
            float4 v = *(const float4*)(xf + sb + (long)(ch0 + sch) * 1024 + n0 + sn);
            t[sch][sn] = v.x; t[sch][sn + 1] = v.y;
            t[sch][sn + 2] = v.z; t[sch][sn + 3] = v.w;
        }
    } else {
#pragma unroll
        for (int p = 0; p < 16; ++p) {
            int e = tid + p * 256; int sch = e >> 6, sn = e & 63;
            t[sch][sn] = bfbits2f(((const unsigned short*)x)[sb + (long)(ch0 + sch) * 1024 + n0 + sn]);
        }
    }
    __syncthreads();
#pragma unroll
    for (int p = 0; p < 16; ++p) {
        int e = tid + p * 256; int dn = e >> 6, dch = e & 63;
        dst[db + (long)(n0 + dn) * 256 + ch0 + dch] = __float2bfloat16(t[dch][dn]);
    }
}

// ---------- single-pass column softmax + fused v-scale ------------------------
__global__ __launch_bounds__(256)
void smnorm_kernel(bf16* __restrict__ X, bf16* __restrict__ vb,
                   const unsigned* __restrict__ colmax, int gN, int gq) {
    const int tid = threadIdx.x;
    const int cg = tid & 7;            // col group (8 cols, 16B)
    const int js = tid >> 3;           // row slice (0..31)
    const int n0 = blockIdx.x * 64;
    const long zb = (long)blockIdx.y * 1048576;
    unsigned short* Xp = (unsigned short*)X + zb + n0 + cg * 8;
    const unsigned* cm = colmax + (long)blockIdx.y * 1024 + n0 + cg * 8;

    float M8[8], s8[8];
#pragma unroll
    for (int q = 0; q < 8; ++q) {
        unsigned k = cm[q];
        unsigned b = (k & 0x80000000u) ? (k & 0x7fffffffu) : ~k;
        M8[q] = __uint_as_float(b);
        s8[q] = 0.f;
    }
#pragma unroll 4
    for (int r = 0; r < 32; ++r) {
        long off = (long)(js * 32 + r) * 1024;
        bf16x8v u = *(const bf16x8v*)(Xp + off);
        bf16x8v o;
#pragma unroll
        for (int q = 0; q < 8; ++q) {
            float e = __expf(bfbits2f((unsigned short)u[q]) - M8[q]);
            s8[q] += e;
            o[q] = (short)f2bfbits(e);
        }
        *(bf16x8v*)(Xp + off) = o;
    }
    __shared__ float sh[32][8][8];
    __shared__ float Sc[64];
#pragma unroll
    for (int q = 0; q < 8; ++q) sh[js][cg][q] = s8[q];
    __syncthreads();
    if (tid < 64) {
        float ss = 0.f;
#pragma unroll 8
        for (int s = 0; s < 32; ++s) ss += sh[s][tid >> 3][tid & 7];
        Sc[tid] = 1.0f / ss;
    }
    __syncthreads();
    const int side = (blockIdx.y >= (unsigned)gq) ? 1 : 0;
    const int zl = blockIdx.y - side * gq;
    bf16* vp = vb + (long)(side * 256) * gN + (long)zl * 1024 + n0 + cg * 8;
    float is8[8];
#pragma unroll
    for (int q = 0; q < 8; ++q) is8[q] = Sc[cg * 8 + q];
#pragma unroll
    for (int rr = 0; rr < 8; ++rr) {
        long off = (long)(rr * 32 + js) * gN;
        bf16x8v u = *(bf16x8v*)(vp + off);
        bf16x8v o;
#pragma unroll
        for (int q = 0; q < 8; ++q)
            o[q] = (short)f2bfbits(bfbits2f((unsigned short)u[q]) * is8[q]);
        *(bf16x8v*)(vp + off) = o;
    }
}

// ---------- 256-thread BMx128 NT MFMA GEMM -----------------------------------
// D[z][m][n] = sum_k A[z][m][k] * B[z][n][k]   (both k-contiguous).
// B2=false: NBUF=3 ring (48KB, 3 blk/CU), counted vmcnt, 1 barrier/K-step.
// B2=true:  NBUF=4 pair-window (64KB, 2 blk/CU): per window {vmcnt(0), barrier,
//   stage next pair (issued a full ~1300cy window before its wait), ds_read+MFMA
//   tile a, tile b}. Halves barrier count; drain is ~free since loads were
//   issued one full window earlier. Use only where grid%512==0 (2/CU exact).
// Cross-wave safety (both): all ds_reads of a buffer retire via MFMA lgkm waits
// before their wave reaches the next barrier; stage issues after that barrier.
// XCD swizzle (T1): remap flat id so each XCD owns a contiguous chunk, z slowest.
// EPI: 0 plain bf16 | 1 +bias[row] | 2 *scale+bias[row] + colmax atomics | 3 +res fp32
template <int MI, int EPI, bool B2>
__global__ __launch_bounds__(256)
void mfma_nt(const bf16* __restrict__ A1, const bf16* __restrict__ A2,
             long aB1, long aB2, int ldA1, int ldA2,
             const bf16* __restrict__ B1, const bf16* __restrict__ B2p,
             long bB1, long bB2, int ldB1, int ldB2,
             int ksplit, long kOff2,
             void* __restrict__ out1, void* __restrict__ out2,
             long oB1, long oB2, int ldO1, int ldO2,
             int K, float scale,
             const void* __restrict__ bias1, const void* __restrict__ bias2,
             const void* __restrict__ res1, const void* __restrict__ res2,
             long rBatch, int bofs, int zsplit,
             const int* __restrict__ dflag) {
    constexpr int BM = MI * 32;
    constexpr int NBUF = B2 ? 4 : 3;
    __shared__ short As[NBUF][BM * 32];
    __shared__ short Bs[NBUF][4096];
    const int tid  = threadIdx.x;
    const int lane = tid & 63, wave = tid >> 6;
    const int quad = lane >> 4, lrow = lane & 15;
    const int wm = (wave >> 1) * (MI * 16), wn = (wave & 1) * 64;

    // ---- XCD-aware block swizzle (bijective when ntot % 8 == 0) ----
    int bx = blockIdx.x, by = blockIdx.y, bz = blockIdx.z;
    {
        const int gx = gridDim.x, gy = gridDim.y;
        const int gxy = gx * gy;
        const int ntot = gxy * gridDim.z;
        if ((ntot & 7) == 0) {
            int flat = bx + gx * (by + gy * bz);
            int w = (flat & 7) * (ntot >> 3) + (flat >> 3);
            bz = w / gxy;
            int rem = w - bz * gxy;
            by = rem / gx;
            bx = rem - by * gx;
        }
    }
    const int z  = bz;
    const bool hiz = (z >= zsplit);
    const int zl = hiz ? z - zsplit : z;
    const int n0 = bx * 128, m0 = by * BM;
    const int ldA = hiz ? ldA2 : ldA1, ldB = hiz ? ldB2 : ldB1;
    const int ldO = hiz ? ldO2 : ldO1;
    const int srow = tid >> 2, sseg = tid & 3;
    const int sl = sseg ^ ((srow >> 1) & 3);        // staging: swizzled seg
    const int xq = quad ^ ((lrow >> 1) & 3);        // read: physical seg

    const bf16* Ab = (hiz ? A2 : A1) + (long)zl * (hiz ? aB2 : aB1);
    const bf16* Bb = (hiz ? B2p : B1) + (long)zl * (hiz ? bB2 : bB1);

    auto stage = [&](int buf, int k0) {
        const bf16* asrc = Ab + (long)k0;
        const bf16* bsrc = Bb + ((k0 < ksplit) ? (long)k0 : (long)(k0 - ksplit) + kOff2);
#pragma unroll
        for (int p = 0; p < MI / 2; ++p)
            gl16(asrc + (long)(m0 + p * 64 + srow) * ldA + sl * 8,
                 &As[buf][p * 2048 + wave * 512]);
        gl16(bsrc + (long)(n0 + srow) * ldB + sl * 8, &Bs[buf][wave * 512]);
        gl16(bsrc + (long)(n0 + 64 + srow) * ldB + sl * 8, &Bs[buf][2048 + wave * 512]);
    };
    auto compute = [&](int cur, f32x4v (&acc)[MI][4]) {
        bf16x8v bfr[4], afr[MI];
#pragma unroll
        for (int j = 0; j < 4; ++j)
            bfr[j] = *(const bf16x8v*)&Bs[cur][(wn + j * 16 + lrow) * 32 + xq * 8];
#pragma unroll
        for (int i = 0; i < MI; ++i)
            afr[i] = *(const bf16x8v*)&As[cur][(wm + i * 16 + lrow) * 32 + xq * 8];
        __builtin_amdgcn_s_setprio(1);
#pragma unroll
        for (int i = 0; i < MI; ++i)
#pragma unroll
            for (int j = 0; j < 4; ++j)
                acc[i][j] = __builtin_amdgcn_mfma_f32_16x16x32_bf16(afr[i], bfr[j], acc[i][j], 0, 0, 0);
        __builtin_amdgcn_s_setprio(0);
    };

    f32x4v acc[MI][4] = {};
    const int nt = K >> 5;

    if constexpr (B2) {
        // pair-window loop: nt must be even (all K here are multiples of 64)
        stage(0, 0);
        stage(1, 32);
        const int nw = nt >> 1;
        for (int w = 0; w < nw; ++w) {
            asm volatile("s_waitcnt vmcnt(0)" ::: "memory");
            __builtin_amdgcn_s_barrier();
            __builtin_amdgcn_sched_barrier(0);
            const int cb = (w & 1) ? 2 : 0;      // pair being consumed
            const int sb = (w & 1) ? 0 : 2;      // pair to stage
            if (w + 1 < nw) {
                stage(sb, (2 * w + 2) << 5);
                stage(sb + 1, (2 * w + 3) << 5);
            }
            compute(cb, acc);
            compute(cb + 1, acc);
        }
    } else {
        stage(0, 0);
        if (nt > 1) stage(1, 32);
        int cur = 0;
        for (int t = 0; t < nt; ++t) {
            if (t + 1 < nt) {
                if constexpr (MI == 4) asm volatile("s_waitcnt vmcnt(4)" ::: "memory");
                else                   asm volatile("s_waitcnt vmcnt(3)" ::: "memory");
            } else {
                asm volatile("s_waitcnt vmcnt(0)" ::: "memory");
            }
            __builtin_amdgcn_s_barrier();
            __builtin_amdgcn_sched_barrier(0);
            if (t + 2 < nt) {
                int nb = cur + 2; if (nb >= 3) nb -= 3;
                stage(nb, (t + 2) << 5);
            }
            compute(cur, acc);
            cur = (cur == 2) ? 0 : cur + 1;
        }
    }

    const bool f32 = (*dflag != 0);
    const void* bias = hiz ? bias2 : bias1;
    if (EPI != 3) {
        bf16* O = (bf16*)(hiz ? out2 : out1) + (long)zl * (hiz ? oB2 : oB1);
        float colm[4] = {-3.4e38f, -3.4e38f, -3.4e38f, -3.4e38f};
#pragma unroll
        for (int i = 0; i < MI; ++i) {
            int row0 = m0 + wm + i * 16 + quad * 4;
            float rb[4] = {0.f, 0.f, 0.f, 0.f};
            if (EPI == 1 || EPI == 2) {
#pragma unroll
                for (int r = 0; r < 4; ++r) rb[r] = load1_any(bias, row0 + r, f32);
            }
#pragma unroll
            for (int j = 0; j < 4; ++j) {
                int col = n0 + wn + j * 16 + lrow;
#pragma unroll
                for (int r = 0; r < 4; ++r) {
                    float vv = acc[i][j][r];
                    if (EPI == 1) vv += rb[r];
                    if (EPI == 2) { vv = vv * scale + rb[r]; colm[j] = fmaxf(colm[j], vv); }
                    O[(long)(row0 + r) * ldO + col] = __float2bfloat16(vv);
                }
            }
        }
        if constexpr (EPI == 2) {
            // per-column max of this 128x128 tile -> global ordered-uint atomicMax
            __shared__ float smx[2][128];
#pragma unroll
            for (int off = 16; off < 64; off <<= 1)
#pragma unroll
                for (int j = 0; j < 4; ++j)
                    colm[j] = fmaxf(colm[j], __shfl_xor(colm[j], off));
            if (quad == 0) {
#pragma unroll
                for (int j = 0; j < 4; ++j)
                    smx[wave >> 1][wn + j * 16 + lrow] = colm[j];
            }
            __syncthreads();
            if (tid < 128) {
                float M = fmaxf(smx[0][tid], smx[1][tid]);
                unsigned b = __float_as_uint(M);
                unsigned key = (b & 0x80000000u) ? ~b : (b | 0x80000000u);
                unsigned* cmp = (unsigned*)(hiz ? res2 : res1) + (long)zl * rBatch + n0 + tid;
                atomicMax(cmp, key);
            }
        }
    } else {
        float* O = (float*)(hiz ? out2 : out1);
        const void* res = hiz ? res2 : res1;
        const long ob  = (long)(zl + bofs) * (hiz ? oB2 : oB1);
        const long rbb = (long)(zl + bofs) * rBatch;
#pragma unroll
        for (int i = 0; i < MI; ++i) {
            int row0 = m0 + wm + i * 16 + quad * 4;
#pragma unroll
            for (int j = 0; j < 4; ++j) {
                int col = n0 + wn + j * 16 + lrow;
#pragma unroll
                for (int r = 0; r < 4; ++r) {
                    float rv = load1_any(res, rbb + (long)(row0 + r) * ldO + col, f32);
                    O[ob + (long)(row0 + r) * ldO + col] = acc[i][j][r] + rv;
                }
            }
        }
    }
}

// ---------- LayerNorm + relayout: XV rows 0-255 [256][gN] -> [(z,c)][1024] ----
__global__ __launch_bounds__(256)
void layernorm_kernel(const bf16* __restrict__ src, bf16* __restrict__ dst,
                      const void* __restrict__ g, const void* __restrict__ beta,
                      int gN, const int* __restrict__ dflag) {
    const bool f32 = (*dflag != 0);
    const int zc = blockIdx.x;          // z*256 + c
    const int zz = zc >> 8, c = zc & 255;
    const bf16* p = src + (long)c * gN + (long)zz * 1024;
    bf16* q = dst + (long)zc * 1024;
    const int tid = threadIdx.x;
    float4 v = loadbf4(p + tid * 4);
    float s  = v.x + v.y + v.z + v.w;
    float ss = v.x * v.x + v.y * v.y + v.z * v.z + v.w * v.w;
#pragma unroll
    for (int off = 32; off > 0; off >>= 1) {
        s  += __shfl_down(s, off);
        ss += __shfl_down(ss, off);
    }
    __shared__ float sh[8];
    __shared__ float sh_mu, sh_rs;
    if ((tid & 63) == 0) { sh[tid >> 6] = s; sh[4 + (tid >> 6)] = ss; }
    __syncthreads();
    if (tid == 0) {
        float S  = sh[0] + sh[1] + sh[2] + sh[3];
        float SS = sh[4] + sh[5] + sh[6] + sh[7];
        float mu = S * (1.0f / 1024.0f);
        float var = SS * (1.0f / 1024.0f) - mu * mu;
        sh_mu = mu;
        sh_rs = rsqrtf(fmaxf(var, 0.0f) + 1e-5f);
    }
    __syncthreads();
    float mu = sh_mu, rs = sh_rs;
    float gx = load1_any(g, tid * 4 + 0, f32), gy = load1_any(g, tid * 4 + 1, f32);
    float gz = load1_any(g, tid * 4 + 2, f32), gw = load1_any(g, tid * 4 + 3, f32);
    float bx = load1_any(beta, tid * 4 + 0, f32), by = load1_any(beta, tid * 4 + 1, f32);
    float bz = load1_any(beta, tid * 4 + 2, f32), bw = load1_any(beta, tid * 4 + 3, f32);
    store_bf4(q + tid * 4,
              (v.x - mu) * rs * gx + bx, (v.y - mu) * rs * gy + by,
              (v.z - mu) * rs * gz + bz, (v.w - mu) * rs * gw + bw);
}

// ---------- host ---------------------------------------------------------------
extern "C" void kernel_launch(void* const* d_in, const int* in_sizes, int n_in,
                              void* d_out, int out_size, void* d_ws, size_t ws_size,
                              hipStream_t stream) {
    const void* x_spa  = d_in[0];
    const void* x_freq = d_in[1];
    const void* w_cdc  = d_in[2];
    const void* b_cdc  = d_in[3];
    const void* w_sv   = d_in[4];
    const void* b_sv   = d_in[5];
    const void* w_fv   = d_in[6];
    const void* b_fv   = d_in[7];
    const void* ln_w   = d_in[8];
    const void* ln_b   = d_in[9];
    const void* w_qk   = d_in[10];
    const void* w_spa  = d_in[11];
    const void* b_spa  = d_in[12];
    const void* w_frq  = d_in[13];
    const void* b_frq  = d_in[14];
    float* out = (float*)d_out;          // fp32 output

    const int B = 16, C = 256;
    const long XB = 262144;              // 256*1024 elems
    const long PB = 1048576;             // 1024*1024 elems

    // header: dflag[0..1] at offset 0, bcat fp32[768] at offset 1024
    int*   dflag = (int*)d_ws;
    float* bcat  = (float*)((char*)d_ws + 1024);
    bf16*  wb    = (bf16*)((char*)d_ws + 4096);
    bf16* w_cdc_b = wb;                       // 131072  (256 x 512)
    bf16* w_sv_b  = w_cdc_b + 131072;         // 65536
    bf16* w_fv_b  = w_sv_b  + 65536;          // 65536
    bf16* w_qk_b  = w_fv_b  + 65536;          // 2097152 (lo 1M | hi 1M -> W1s)
    bf16* w_spa_b = w_qk_b  + 2097152;        // 1048576
    bf16* w_frq_b = w_spa_b + 1048576;        // 1048576
    bf16* w_qk_hiT= w_frq_b + 1048576;        // 1048576 (w_qk_hi^T copy)
    bf16* W1f     = w_qk_hiT + 1048576;       // 1048576 (w_frq @ w_qk_hi)
    bf16* Wleft   = W1f + 1048576;            // 393216  (768 x 512)
    bf16* pb      = Wleft + 393216;

    const size_t fixedB = 4096 + 6946816ull * 2;     // 13,897,728
    const size_t perB   = 8921088ull;                // 9*XB*2 + 2*PB*2 + 8192
    size_t avail = (ws_size > fixedB) ? (ws_size - fixedB) : 0;
    long gmax = (long)(avail / perB);
    const bool wsOK = (gmax >= 1);
    int G = wsOK ? (int)(gmax > 16 ? 16 : gmax) : 1;

    bf16* xT    = pb;                      // [2g][1024][256]  (spa z<g | frq)
    bf16* XV    = xT  + 2L * G * XB;       // [768][gN]: xlnF 0-255 | vb 256-767
    bf16* xln2  = XV  + 3L * G * XB;       // [(z,c)][1024]  post-LN
    bf16* qTT   = xln2 + (long)G * XB;     // [3][1024][g*256]: qT | TTs | TTf
    bf16* attpT = qTT + 3L * G * XB;       // [2g][1024][1024] scores^T -> E
    unsigned* colmax = (unsigned*)(attpT + 2L * G * PB);   // [2g][1024] keys

    dim3 blk(256);
    detect_kernel<<<dim3(1), dim3(1024), 0, stream>>>((const unsigned short*)x_spa, dflag);

    if (!wsOK) {
        float mb = (float)(ws_size >> 20);
        diag_kernel<<<dim3(1), dim3(64), 0, stream>>>(out, 1000.0f * (mb + 1.0f));
        return;
    }

    // ---- setup: weights->bf16 + Wleft + bcat (one dispatch), w_qk_hi^T, W1 GEMM
    convert6_kernel<<<dim3(4352), blk, 0, stream>>>(
        w_cdc, w_sv, w_fv, w_qk, w_spa, w_frq, b_cdc, b_sv, b_fv,
        wb, Wleft, bcat, dflag);
    xpose_w_kernel<<<dim3(16, 16), blk, 0, stream>>>(w_qk_b + 1048576, w_qk_hiT);
    // W1s overwrites w_qk_hi slot (dead after transpose); W1f separate.
    mfma_nt<4, 0, true><<<dim3(8, 8, 2), blk, 0, stream>>>(
        w_spa_b, w_frq_b, 0, 0, 1024, 1024,
        w_qk_hiT, w_qk_hiT, 0, 0, 1024, 1024, 1024, 0,
        w_qk_b + 1048576, W1f, 0, 0, 1024, 1024,
        1024, 1.0f, nullptr, nullptr, nullptr, nullptr, 0, 0, 1, dflag);

    for (int b0 = 0; b0 < B; b0 += G) {
        int g = (B - b0 < G) ? (B - b0) : G;
        const int gN = g * 1024;
        bf16* vb = XV + 256L * gN;

        // x_spa/x_freq -> xT (bf16, [(z,n)][ch]); also init colmax[2g][1024]
        xpose_conv_kernel<<<dim3(16, 4, 2 * g), blk, 0, stream>>>(
            x_spa, x_freq, xT, colmax, b0, g, dflag);

        // XV[768][gN] = Wleft @ cat_k(x_spa,x_freq) + bcat  (K split at 256)
        mfma_nt<4, 1, false><<<dim3(8 * g, 6, 1), blk, 0, stream>>>(
            Wleft, Wleft, 0, 0, 512, 512,
            xT, xT, 0, 0, 256, 256, 256, (long)g * XB,
            XV, XV, 0, 0, gN, gN,
            512, 1.0f, bcat, bcat, nullptr, nullptr, 0, 0, 1, dflag + 1);

        // LN over n (1024) + relayout -> xln2[(z,c)][1024]
        layernorm_kernel<<<dim3(g * C), blk, 0, stream>>>(XV, xln2, ln_w, ln_b, gN, dflag);

        // qTT[3][1024][g*256] = [w_qk_lo; W1s; W1f] . xln2
        mfma_nt<4, 0, false><<<dim3(2 * g, 8, 3), blk, 0, stream>>>(
            w_qk_b, W1f, 1048576, 0, 1024, 1024,
            xln2, xln2, 0, 0, 1024, 1024, 1024, 0,
            qTT, qTT + 2L * g * XB, (long)g * XB, 0, g * 256, g * 256,
            1024, 1.0f, nullptr, nullptr, nullptr, nullptr, 0, 0, 2, dflag);

        // attpT[side][z][j][n] = scale*(TT_side[j].qT[n]) + bias[j]; colmax atomics
        mfma_nt<4, 2, true><<<dim3(8, 8, 2 * g), blk, 0, stream>>>(
            qTT + (long)g * XB, qTT + 2L * g * XB, 256, 256, g * 256, g * 256,
            qTT, qTT, 256, 256, g * 256, g * 256, 256, 0,
            attpT, attpT + (long)g * PB, PB, PB, 1024, 1024,
            256, 0.03125f, b_spa, b_frq, colmax, colmax + (long)g * 1024,
            1024, 0, g, dflag);

        // single-pass column softmax + fused v-scale
        smnorm_kernel<<<dim3(16, 2 * g), blk, 0, stream>>>(attpT, vb, colmax, gN, g);

        // out[z][c][j] = sum_n vb[c][(z,n)] E[j][n] + x   (fp32)
        mfma_nt<4, 3, true><<<dim3(8, 2, 2 * g), blk, 0, stream>>>(
            vb, vb + 256L * gN, 1024, 1024, gN, gN,
            attpT, attpT + (long)g * PB, PB, PB, 1024, 1024, 1024, 0,
            out, out + 4194304, XB, XB, 1024, 1024,
            1024, 1.0f, nullptr, nullptr, x_spa, x_freq, XB, b0, g, dflag);
    }
}